// Round 10
// baseline (68.730 us; speedup 1.0000x reference)
//
#include <hip/hip_runtime.h>
#include <float.h>
#include <limits.h>

#define N_ROWS 8192
#define D_COLS 4096
#define RANK_BLOCKS 512   // 16 elements per block
#define SHIFT 8192.0f     // E[Err]; Sterbenz-exact subtraction for Err in [4096,16384]

typedef float f32x4 __attribute__((ext_vector_type(4)));

// Kernel 1: Err[row] = sum_j (in[row][j] - tg[row][j])^2
// One wave per row, ext-vector f32x4 loads. R10 A/B: plain (cacheable) loads
// instead of nontemporal -- testing whether the L3 (which holds ~134 MB of
// the 268 MB input across replays, per R1/R2 FETCH_SIZE) can serve half the
// stream concurrently with HBM, dropping row time toward ~134MB/6.3TB/s.
__global__ __launch_bounds__(256) void row_sqerr_kernel(
    const float* __restrict__ in, const float* __restrict__ tg,
    float* __restrict__ err) {
  const int row = (blockIdx.x << 2) | (threadIdx.x >> 6);
  const int lane = threadIdx.x & 63;
  const f32x4* a = (const f32x4*)(in + (size_t)row * D_COLS) + lane;
  const f32x4* b = (const f32x4*)(tg + (size_t)row * D_COLS) + lane;

  float acc0 = 0.f, acc1 = 0.f, acc2 = 0.f, acc3 = 0.f;
  f32x4 xa[8], xb[8];

#pragma unroll
  for (int s = 0; s < 2; ++s) {
#pragma unroll
    for (int p = 0; p < 8; ++p) xa[p] = a[(s * 8 + p) * 64];
#pragma unroll
    for (int p = 0; p < 8; ++p) xb[p] = b[(s * 8 + p) * 64];
#pragma unroll
    for (int p = 0; p < 8; ++p) {
      f32x4 d = xa[p] - xb[p];
      acc0 += d.x * d.x;
      acc1 += d.y * d.y;
      acc2 += d.z * d.z;
      acc3 += d.w * d.w;
    }
  }
  float acc = (acc0 + acc1) + (acc2 + acc3);
#pragma unroll
  for (int off = 32; off > 0; off >>= 1) acc += __shfl_down(acc, off);
  if (lane == 0) err[row] = acc;
}

// Kernel 2: fused rank + objective, f32 inner loop on SHIFTED values.
// (unchanged from R9 -- see notes there)
__global__ __launch_bounds__(256) void rank_obj_kernel(
    const float* __restrict__ err, double* __restrict__ cand_num,
    int* __restrict__ cand_idx, double* __restrict__ cand_c1,
    double* __restrict__ totals) {
  __shared__ float s[N_ROWS];
  __shared__ double wc[4], wq[4], sCQ[2];
  __shared__ double lnum[16], lc1[16];
  __shared__ int lidx[16];

  const int t = threadIdx.x;

  f32x4* s4w = (f32x4*)s;
  const f32x4* e4 = (const f32x4*)err;
#pragma unroll
  for (int k = 0; k < 8; ++k) s4w[t + (k << 8)] = e4[t + (k << 8)];
  __syncthreads();

  const f32x4* s4 = (const f32x4*)s;

  double tc = 0.0, tq = 0.0;
#pragma unroll
  for (int k = 0; k < 8; ++k) {
    f32x4 c = s4[t + (k << 8)];
#pragma unroll
    for (int u = 0; u < 4; ++u) {
      double d = (double)(c[u] - SHIFT);
      tc += d;
      tq = fma(d, d, tq);
    }
  }
#pragma unroll
  for (int off = 32; off > 0; off >>= 1) {
    tc += __shfl_down(tc, off);
    tq += __shfl_down(tq, off);
  }
  if ((t & 63) == 0) { wc[t >> 6] = tc; wq[t >> 6] = tq; }
  __syncthreads();
  if (t == 0) {
    sCQ[0] = ((wc[0] + wc[1]) + (wc[2] + wc[3]));
    sCQ[1] = ((wq[0] + wq[1]) + (wq[2] + wq[3]));
  }
  __syncthreads();
  const double Cp = sCQ[0], Qp = sCQ[1];

  const int g = t & 15;
  const int le = t >> 4;
  const int e = (blockIdx.x << 4) | le;
  const float v = s[e];
  const unsigned long long ke =
      ((unsigned long long)__float_as_uint(v) << 13) | (unsigned)e;

  int cnt = 0;
  float c1 = 0.f, q1 = 0.f;
#pragma unroll 4
  for (int k = 0; k < 128; ++k) {
    const int i4 = (g << 7) | ((k + g) & 127);
    const f32x4 c = s4[i4];
    const int j = i4 << 2;
#pragma unroll
    for (int u = 0; u < 4; ++u) {
      unsigned long long kj =
          ((unsigned long long)__float_as_uint(c[u]) << 13) | (unsigned)(j + u);
      bool lt = kj < ke;
      cnt += lt;
      float w = c[u] - SHIFT;
      float d = lt ? w : 0.f;
      c1 += d;
      q1 = fmaf(d, d, q1);
    }
  }
#pragma unroll
  for (int off = 1; off < 16; off <<= 1) {
    cnt += __shfl_xor(cnt, off);
    c1 += __shfl_xor(c1, off);
    q1 += __shfl_xor(q1, off);
  }

  if (g == 0) {
    float we = v - SHIFT;
    double c1i = (double)c1 + (double)we;
    double q1i = (double)q1 + (double)we * (double)we;
    double num;
    if (cnt == N_ROWS - 1) {
      num = 1e300;
    } else {
      double n1 = (double)(cnt + 1);
      double n2 = (double)(N_ROWS - 1 - cnt);
      double c2 = Cp - c1i;
      num = Qp - c1i * c1i / n1 - c2 * c2 / n2;
    }
    lnum[le] = num;
    lidx[le] = cnt;
    lc1[le] = c1i;
  }
  __syncthreads();

  if (t == 0) {
    double bn = lnum[0];
    int bi = lidx[0];
    double bc = lc1[0];
#pragma unroll
    for (int w = 1; w < 16; ++w) {
      if (lnum[w] < bn || (lnum[w] == bn && lidx[w] < bi)) {
        bn = lnum[w]; bi = lidx[w]; bc = lc1[w];
      }
    }
    cand_num[blockIdx.x] = bn;
    cand_idx[blockIdx.x] = bi;
    cand_c1[blockIdx.x] = bc;
    if (blockIdx.x == 0) { totals[0] = Cp; totals[1] = Qp; }
  }
}

// Kernel 3: tiny final reduce over 512 block-winners (1 wave).
__global__ __launch_bounds__(64) void final_kernel(
    const double* __restrict__ cand_num, const int* __restrict__ cand_idx,
    const double* __restrict__ cand_c1, const double* __restrict__ totals,
    float* __restrict__ out) {
  const int t = threadIdx.x;
  double bn = DBL_MAX;
  int bi = INT_MAX;
  double bc = 0.0;
#pragma unroll
  for (int k = 0; k < 8; ++k) {
    int i = t + (k << 6);
    double n = cand_num[i];
    int ix = cand_idx[i];
    double c = cand_c1[i];
    if (n < bn || (n == bn && ix < bi)) { bn = n; bi = ix; bc = c; }
  }
#pragma unroll
  for (int off = 1; off < 64; off <<= 1) {
    double n2 = __shfl_xor(bn, off);
    int i2 = __shfl_xor(bi, off);
    double c2 = __shfl_xor(bc, off);
    if (n2 < bn || (n2 == bn && i2 < bi)) { bn = n2; bi = i2; bc = c2; }
  }
  if (t == 0) {
    double Cp = totals[0], Qp = totals[1];
    double Sb = Qp - Cp * Cp / (double)N_ROWS;
    double T = (double)(bi + 1);
    double inlier_sum = bc + T * (double)SHIFT;
    out[0] = (float)(inlier_sum / T + 0.1 * (bn / Sb));
  }
}

extern "C" void kernel_launch(void* const* d_in, const int* in_sizes, int n_in,
                              void* d_out, int out_size, void* d_ws, size_t ws_size,
                              hipStream_t stream) {
  const float* input = (const float*)d_in[0];
  const float* target = (const float*)d_in[1];
  float* out = (float*)d_out;

  double* cand_num = (double*)d_ws;                   // 512 f64
  double* cand_c1 = cand_num + RANK_BLOCKS;           // 512 f64
  double* totals = cand_c1 + RANK_BLOCKS;             // 2 f64
  int* cand_idx = (int*)(totals + 2);                 // 512 i32
  float* err = (float*)(cand_idx + RANK_BLOCKS);      // 8192 f32

  row_sqerr_kernel<<<N_ROWS / 4, 256, 0, stream>>>(input, target, err);
  rank_obj_kernel<<<RANK_BLOCKS, 256, 0, stream>>>(err, cand_num, cand_idx,
                                                   cand_c1, totals);
  final_kernel<<<1, 64, 0, stream>>>(cand_num, cand_idx, cand_c1, totals, out);
}

// Round 11
// 62.735 us; speedup vs baseline: 1.0956x; 1.0956x over previous
//
#include <hip/hip_runtime.h>
#include <float.h>
#include <limits.h>

#define N_ROWS 8192
#define D_COLS 4096
#define RANK_BLOCKS 512   // 16 elements per block (4 per wave)
#define SHIFT 8192.0f     // E[Err]; Sterbenz-exact for Err in [4096,16384]

typedef float f32x4 __attribute__((ext_vector_type(4)));

// Kernel 1: Err[row] = sum_j (in[row][j] - tg[row][j])^2
// One wave per row, nontemporal loads. Timed ~43.5 us = 268 MB at ~6.2 TB/s
// effective (L3 serves ~half concurrently) = fabric-level roofline.
__global__ __launch_bounds__(256) void row_sqerr_kernel(
    const float* __restrict__ in, const float* __restrict__ tg,
    float* __restrict__ err) {
  const int row = (blockIdx.x << 2) | (threadIdx.x >> 6);
  const int lane = threadIdx.x & 63;
  const f32x4* a = (const f32x4*)(in + (size_t)row * D_COLS) + lane;
  const f32x4* b = (const f32x4*)(tg + (size_t)row * D_COLS) + lane;

  float acc0 = 0.f, acc1 = 0.f, acc2 = 0.f, acc3 = 0.f;
  f32x4 xa[8], xb[8];

#pragma unroll
  for (int s = 0; s < 2; ++s) {
#pragma unroll
    for (int p = 0; p < 8; ++p) xa[p] = __builtin_nontemporal_load(&a[(s * 8 + p) * 64]);
#pragma unroll
    for (int p = 0; p < 8; ++p) xb[p] = __builtin_nontemporal_load(&b[(s * 8 + p) * 64]);
#pragma unroll
    for (int p = 0; p < 8; ++p) {
      f32x4 d = xa[p] - xb[p];
      acc0 += d.x * d.x;
      acc1 += d.y * d.y;
      acc2 += d.z * d.z;
      acc3 += d.w * d.w;
    }
  }
  float acc = (acc0 + acc1) + (acc2 + acc3);
#pragma unroll
  for (int off = 32; off > 0; off >>= 1) acc += __shfl_down(acc, off);
  if (lane == 0) err[row] = acc;
}

// Kernel 2: fused rank + objective, register-tiled 4 elements per wave.
// Each wave owns 4 candidate elements (u64 lex keys in registers); each lane
// scans a 128-value slice of LDS, amortizing key-build + shift across the 4
// compares (5 ops/pair vs 8). rank = #{lex-less}, c1' = sum of lex-less
// shifted values (f32; shift removes cancellation). Element e IS the split
// candidate at i=rank (bijection): Sw1+Sw2 = Q' - c1'^2/n1 - c2'^2/n2.
__global__ __launch_bounds__(256) void rank_obj_kernel(
    const float* __restrict__ err, double* __restrict__ cand_num,
    int* __restrict__ cand_idx, double* __restrict__ cand_c1,
    double* __restrict__ totals) {
  __shared__ float s[N_ROWS];
  __shared__ double wc[4], wq[4], sCQ[2];
  __shared__ double lnum[16], lc1[16];
  __shared__ int lidx[16];

  const int t = threadIdx.x;

  // stage all errs into LDS (vectorized, coalesced)
  f32x4* s4w = (f32x4*)s;
  const f32x4* e4 = (const f32x4*)err;
#pragma unroll
  for (int k = 0; k < 8; ++k) s4w[t + (k << 8)] = e4[t + (k << 8)];
  __syncthreads();

  const f32x4* s4 = (const f32x4*)s;

  // shifted grand totals C' , Q' in f64 (identical every block; blk 0 publishes)
  double tc = 0.0, tq = 0.0;
#pragma unroll
  for (int k = 0; k < 8; ++k) {
    f32x4 c = s4[t + (k << 8)];
#pragma unroll
    for (int u = 0; u < 4; ++u) {
      double d = (double)(c[u] - SHIFT);
      tc += d;
      tq = fma(d, d, tq);
    }
  }
#pragma unroll
  for (int off = 32; off > 0; off >>= 1) {
    tc += __shfl_down(tc, off);
    tq += __shfl_down(tq, off);
  }
  if ((t & 63) == 0) { wc[t >> 6] = tc; wq[t >> 6] = tq; }
  __syncthreads();
  if (t == 0) {
    sCQ[0] = ((wc[0] + wc[1]) + (wc[2] + wc[3]));
    sCQ[1] = ((wq[0] + wq[1]) + (wq[2] + wq[3]));
  }
  __syncthreads();
  const double Cp = sCQ[0], Qp = sCQ[1];

  // wave w owns elements ebase..ebase+3; lane scans values [lane*128, +128)
  const int lane = t & 63;
  const int w = t >> 6;
  const int ebase = (blockIdx.x << 4) | (w << 2);

  unsigned long long ke[4];
#pragma unroll
  for (int m = 0; m < 4; ++m) {
    float v = s[ebase + m];
    ke[m] = ((unsigned long long)__float_as_uint(v) << 13) | (unsigned)(ebase + m);
  }

  int cnt0 = 0, cnt1 = 0, cnt2 = 0, cnt3 = 0;
  float c10 = 0.f, c11 = 0.f, c12 = 0.f, c13 = 0.f;
#pragma unroll 4
  for (int i = 0; i < 32; ++i) {
    const int i4 = (lane << 5) | ((i + lane) & 31);  // staggered slice read
    const f32x4 c = s4[i4];
    const int j = i4 << 2;
#pragma unroll
    for (int u = 0; u < 4; ++u) {
      const unsigned long long kj =
          ((unsigned long long)__float_as_uint(c[u]) << 13) | (unsigned)(j + u);
      const float wv = c[u] - SHIFT;
      bool lt;
      lt = kj < ke[0]; cnt0 += lt; c10 += lt ? wv : 0.f;
      lt = kj < ke[1]; cnt1 += lt; c11 += lt ? wv : 0.f;
      lt = kj < ke[2]; cnt2 += lt; c12 += lt ? wv : 0.f;
      lt = kj < ke[3]; cnt3 += lt; c13 += lt ? wv : 0.f;
    }
  }
  // full-wave reduce of the 4 (cnt, c1) pairs
#pragma unroll
  for (int off = 32; off > 0; off >>= 1) {
    cnt0 += __shfl_down(cnt0, off); c10 += __shfl_down(c10, off);
    cnt1 += __shfl_down(cnt1, off); c11 += __shfl_down(c11, off);
    cnt2 += __shfl_down(cnt2, off); c12 += __shfl_down(c12, off);
    cnt3 += __shfl_down(cnt3, off); c13 += __shfl_down(c13, off);
  }

  if (lane == 0) {
    int cnts[4] = {cnt0, cnt1, cnt2, cnt3};
    float c1s[4] = {c10, c11, c12, c13};
#pragma unroll
    for (int m = 0; m < 4; ++m) {
      float we = s[ebase + m] - SHIFT;
      double c1i = (double)c1s[m] + (double)we;   // inliers = lex <= e
      double num;
      if (cnts[m] == N_ROWS - 1) {
        num = 1e300;                               // i = N-1 invalid split
      } else {
        double n1 = (double)(cnts[m] + 1);
        double n2 = (double)(N_ROWS - 1 - cnts[m]);
        double c2 = Cp - c1i;
        num = Qp - c1i * c1i / n1 - c2 * c2 / n2;  // Sw1+Sw2, shifted form
      }
      const int li = (w << 2) | m;
      lnum[li] = num;
      lidx[li] = cnts[m];
      lc1[li] = c1i;
    }
  }
  __syncthreads();

  if (t == 0) {
    double bn = lnum[0];
    int bi = lidx[0];
    double bc = lc1[0];
#pragma unroll
    for (int q = 1; q < 16; ++q) {
      if (lnum[q] < bn || (lnum[q] == bn && lidx[q] < bi)) {
        bn = lnum[q]; bi = lidx[q]; bc = lc1[q];
      }
    }
    cand_num[blockIdx.x] = bn;
    cand_idx[blockIdx.x] = bi;
    cand_c1[blockIdx.x] = bc;
    if (blockIdx.x == 0) { totals[0] = Cp; totals[1] = Qp; }
  }
}

// Kernel 3: tiny final reduce over 512 block-winners (1 wave).
__global__ __launch_bounds__(64) void final_kernel(
    const double* __restrict__ cand_num, const int* __restrict__ cand_idx,
    const double* __restrict__ cand_c1, const double* __restrict__ totals,
    float* __restrict__ out) {
  const int t = threadIdx.x;
  double bn = DBL_MAX;
  int bi = INT_MAX;
  double bc = 0.0;
#pragma unroll
  for (int k = 0; k < 8; ++k) {
    int i = t + (k << 6);
    double n = cand_num[i];
    int ix = cand_idx[i];
    double c = cand_c1[i];
    if (n < bn || (n == bn && ix < bi)) { bn = n; bi = ix; bc = c; }
  }
#pragma unroll
  for (int off = 1; off < 64; off <<= 1) {
    double n2 = __shfl_xor(bn, off);
    int i2 = __shfl_xor(bi, off);
    double c2 = __shfl_xor(bc, off);
    if (n2 < bn || (n2 == bn && i2 < bi)) { bn = n2; bi = i2; bc = c2; }
  }
  if (t == 0) {
    double Cp = totals[0], Qp = totals[1];
    double Sb = Qp - Cp * Cp / (double)N_ROWS;   // shift-invariant
    double T = (double)(bi + 1);
    double inlier_sum = bc + T * (double)SHIFT;  // un-shift c1
    out[0] = (float)(inlier_sum / T + 0.1 * (bn / Sb));
  }
}

extern "C" void kernel_launch(void* const* d_in, const int* in_sizes, int n_in,
                              void* d_out, int out_size, void* d_ws, size_t ws_size,
                              hipStream_t stream) {
  const float* input = (const float*)d_in[0];
  const float* target = (const float*)d_in[1];
  float* out = (float*)d_out;

  double* cand_num = (double*)d_ws;                   // 512 f64
  double* cand_c1 = cand_num + RANK_BLOCKS;           // 512 f64
  double* totals = cand_c1 + RANK_BLOCKS;             // 2 f64
  int* cand_idx = (int*)(totals + 2);                 // 512 i32
  float* err = (float*)(cand_idx + RANK_BLOCKS);      // 8192 f32

  row_sqerr_kernel<<<N_ROWS / 4, 256, 0, stream>>>(input, target, err);
  rank_obj_kernel<<<RANK_BLOCKS, 256, 0, stream>>>(err, cand_num, cand_idx,
                                                   cand_c1, totals);
  final_kernel<<<1, 64, 0, stream>>>(cand_num, cand_idx, cand_c1, totals, out);
}